// Round 2
// baseline (101.853 us; speedup 1.0000x reference)
//
#include <hip/hip_runtime.h>
#include <hip/hip_bf16.h>

#ifndef __has_builtin
#define __has_builtin(x) 0
#endif

__device__ __forceinline__ float fast_exp2(float x) {
#if __has_builtin(__builtin_amdgcn_exp2f)
  return __builtin_amdgcn_exp2f(x);
#else
  return __exp2f(x);
#endif
}
__device__ __forceinline__ float fast_rcp(float x) {
#if __has_builtin(__builtin_amdgcn_rcpf)
  return __builtin_amdgcn_rcpf(x);
#else
  return 1.0f / x;
#endif
}

#define B_   16
#define NQ_  256
#define NK_  256
#define D_   256
#define QT   2
// tanh(x) = 1 - 2/(1 + exp2(x * 2*log2(e)))
// Split-exp: exp2(s*(hq+hk)) = Eq * Ek with Eq=exp2(s*hq), Ek=exp2(s*hk).
#define TANH_SCALE 2.8853900817779268f
#define LOG2E      1.4426950408889634f

// ---------------- projection GEMM (f32 vector ALU; no f32 MFMA on CDNA4) ----
// z=0: Eq = exp2(TANH_SCALE*(queries@Wq + b1))   [4096,256]
// z=1: Ek = exp2(TANH_SCALE*(keys@Wk))           [4096,256]
__global__ __launch_bounds__(256) void proj_kernel(
    const float* __restrict__ queries, const float* __restrict__ keys,
    const float* __restrict__ Wq, const float* __restrict__ Wk,
    const float* __restrict__ b1,
    float* __restrict__ eqs, float* __restrict__ eks)
{
  const int z = blockIdx.z;
  const float* __restrict__ X = z ? keys : queries;
  const float* __restrict__ W = z ? Wk : Wq;
  float* __restrict__ O = z ? eks : eqs;

  const int m0 = blockIdx.x * 64;
  const int n0 = blockIdx.y * 64;
  const int t  = threadIdx.x;
  const int tx = t & 15, ty = t >> 4;

  __shared__ float As_t[64][68];  // [k][m], padded
  __shared__ float Bs[64][68];    // [k][n]

  float acc[4][4] = {};

  for (int kt = 0; kt < 4; ++kt) {
    const int k0 = kt * 64;
    #pragma unroll
    for (int i = 0; i < 4; ++i) {          // A tile, stored transposed
      int f = t + 256 * i;
      int row = f >> 4;
      int kc  = (f & 15) << 2;
      float4 v = *(const float4*)&X[(size_t)(m0 + row) * D_ + (k0 + kc)];
      As_t[kc + 0][row] = v.x; As_t[kc + 1][row] = v.y;
      As_t[kc + 2][row] = v.z; As_t[kc + 3][row] = v.w;
    }
    #pragma unroll
    for (int i = 0; i < 4; ++i) {          // B tile
      int f = t + 256 * i;
      int kr = f >> 4;
      int nc = (f & 15) << 2;
      *(float4*)&Bs[kr][nc] = *(const float4*)&W[(size_t)(k0 + kr) * D_ + (n0 + nc)];
    }
    __syncthreads();
    #pragma unroll 8
    for (int k = 0; k < 64; ++k) {
      float4 a = *(const float4*)&As_t[k][ty << 2];
      float4 b = *(const float4*)&Bs[k][tx << 2];
      float aa[4] = {a.x, a.y, a.z, a.w};
      float bb[4] = {b.x, b.y, b.z, b.w};
      #pragma unroll
      for (int i = 0; i < 4; ++i)
        #pragma unroll
        for (int j = 0; j < 4; ++j)
          acc[i][j] = fmaf(aa[i], bb[j], acc[i][j]);
    }
    __syncthreads();
  }

  float bias[4] = {0.f, 0.f, 0.f, 0.f};
  if (z == 0) {
    #pragma unroll
    for (int j = 0; j < 4; ++j) bias[j] = b1[n0 + (tx << 2) + j];
  }
  #pragma unroll
  for (int i = 0; i < 4; ++i)
    #pragma unroll
    for (int j = 0; j < 4; ++j)
      O[(size_t)(m0 + (ty << 2) + i) * D_ + n0 + (tx << 2) + j] =
          fast_exp2(TANH_SCALE * (acc[i][j] + bias[j]));
}

// ---------------- fused logits + softmax + PV ------------------------------
// Block = (b, 2 queries). Thread t = key index for logits, value dim for PV.
// logit_eff = -2 * sum_d w2[d] * rcp(1 + Eq[d]*Ek[d])   (consts dropped)
// 1-D grid with b = wgid&15: each XCD (wgid%8 round-robin) sees only 2
// batches -> per-XCD working set ~1.5 MB, L2-resident.
__global__ __launch_bounds__(256, 8) void attn_kernel(
    const float* __restrict__ eqs, const float* __restrict__ eks,
    const float* __restrict__ values, const float* __restrict__ w2,
    float* __restrict__ out)
{
  const int wgid = blockIdx.x;
  const int b  = wgid & 15;
  const int q0 = (wgid >> 4) * QT;
  const int t  = threadIdx.x;
  const int lane = t & 63, wave = t >> 6;

  __shared__ float eq4[QT][D_];    // [qi][d], float4 broadcast reads
  __shared__ float w2s[D_];
  __shared__ float attn4[NK_][QT];
  __shared__ float redA[4][QT], redB[4][QT];

  w2s[t] = w2[t];
  #pragma unroll
  for (int qi = 0; qi < QT; ++qi)
    eq4[qi][t] = eqs[(size_t)(b * NQ_ + q0 + qi) * D_ + t];
  __syncthreads();

  const float* __restrict__ ekrow = eks + (size_t)(b * NK_ + t) * D_;
  float acc0 = 0.f, acc1 = 0.f;
  float4 ekv = *(const float4*)&ekrow[0];
  #pragma unroll 4
  for (int d4 = 0; d4 < D_ / 4 - 1; ++d4) {
    float4 cur = ekv;
    ekv = *(const float4*)&ekrow[(d4 + 1) << 2];
    float4 e0 = *(const float4*)&eq4[0][d4 << 2];
    float4 e1 = *(const float4*)&eq4[1][d4 << 2];
    float4 wv = *(const float4*)&w2s[d4 << 2];
    float c[4]  = {cur.x, cur.y, cur.z, cur.w};
    float a0[4] = {e0.x, e0.y, e0.z, e0.w};
    float a1[4] = {e1.x, e1.y, e1.z, e1.w};
    float wa[4] = {wv.x, wv.y, wv.z, wv.w};
    #pragma unroll
    for (int j = 0; j < 4; ++j) {
      float t0 = fmaf(a0[j], c[j], 1.0f);
      acc0 = fmaf(wa[j], fast_rcp(t0), acc0);
      float t1 = fmaf(a1[j], c[j], 1.0f);
      acc1 = fmaf(wa[j], fast_rcp(t1), acc1);
    }
  }
  {  // peeled last iter
    const int d4 = D_ / 4 - 1;
    float4 cur = ekv;
    float4 e0 = *(const float4*)&eq4[0][d4 << 2];
    float4 e1 = *(const float4*)&eq4[1][d4 << 2];
    float4 wv = *(const float4*)&w2s[d4 << 2];
    float c[4]  = {cur.x, cur.y, cur.z, cur.w};
    float a0[4] = {e0.x, e0.y, e0.z, e0.w};
    float a1[4] = {e1.x, e1.y, e1.z, e1.w};
    float wa[4] = {wv.x, wv.y, wv.z, wv.w};
    #pragma unroll
    for (int j = 0; j < 4; ++j) {
      float t0 = fmaf(a0[j], c[j], 1.0f);
      acc0 = fmaf(wa[j], fast_rcp(t0), acc0);
      float t1 = fmaf(a1[j], c[j], 1.0f);
      acc1 = fmaf(wa[j], fast_rcp(t1), acc1);
    }
  }

  float logit[QT] = {-2.0f * acc0, -2.0f * acc1};

  // block-wide max per query row
  #pragma unroll
  for (int qi = 0; qi < QT; ++qi) {
    float v = logit[qi];
    #pragma unroll
    for (int off = 32; off; off >>= 1) v = fmaxf(v, __shfl_xor(v, off, 64));
    if (lane == 0) redA[wave][qi] = v;
  }
  __syncthreads();
  float mx[QT];
  #pragma unroll
  for (int qi = 0; qi < QT; ++qi)
    mx[qi] = fmaxf(fmaxf(redA[0][qi], redA[1][qi]),
                   fmaxf(redA[2][qi], redA[3][qi]));

  float p[QT];
  #pragma unroll
  for (int qi = 0; qi < QT; ++qi) {
    p[qi] = fast_exp2((logit[qi] - mx[qi]) * LOG2E);
    attn4[t][qi] = p[qi];
  }
  // block-wide sum per query row
  #pragma unroll
  for (int qi = 0; qi < QT; ++qi) {
    float v = p[qi];
    #pragma unroll
    for (int off = 32; off; off >>= 1) v += __shfl_xor(v, off, 64);
    if (lane == 0) redB[wave][qi] = v;
  }
  __syncthreads();
  float inv[QT];
  #pragma unroll
  for (int qi = 0; qi < QT; ++qi)
    inv[qi] = fast_rcp(redB[0][qi] + redB[1][qi] + redB[2][qi] + redB[3][qi]);

  // PV: thread t = value dim; coalesced values reads, attn broadcast from LDS
  float ctx[QT] = {};
  const float* __restrict__ vcol = values + (size_t)b * NK_ * D_ + t;
  #pragma unroll 8
  for (int k = 0; k < NK_; ++k) {
    float val = vcol[(size_t)k * D_];
    float2 av = *(const float2*)&attn4[k][0];
    ctx[0] = fmaf(av.x, val, ctx[0]);
    ctx[1] = fmaf(av.y, val, ctx[1]);
  }
  float* __restrict__ orow = out + (size_t)(b * NQ_ + q0) * D_ + t;
  #pragma unroll
  for (int qi = 0; qi < QT; ++qi) orow[(size_t)qi * D_] = ctx[qi] * inv[qi];
}

extern "C" void kernel_launch(void* const* d_in, const int* in_sizes, int n_in,
                              void* d_out, int out_size, void* d_ws, size_t ws_size,
                              hipStream_t stream)
{
  const float* keys    = (const float*)d_in[0];
  const float* queries = (const float*)d_in[1];
  const float* values  = (const float*)d_in[2];
  const float* Wk      = (const float*)d_in[3];
  const float* Wq      = (const float*)d_in[4];
  const float* b1      = (const float*)d_in[5];
  const float* w2      = (const float*)d_in[6];
  // d_in[7] = b2: dropped (softmax shift-invariance)

  float* eqs = (float*)d_ws;                       // [4096,256] f32, 4 MB
  float* eks = eqs + (size_t)B_ * NQ_ * D_;        // [4096,256] f32, 4 MB
  float* out = (float*)d_out;

  dim3 pgrid(B_ * NQ_ / 64, D_ / 64, 2);           // 64 x 4 x 2 = 512 blocks
  proj_kernel<<<pgrid, 256, 0, stream>>>(queries, keys, Wq, Wk, b1, eqs, eks);

  attn_kernel<<<dim3(B_ * NQ_ / QT), 256, 0, stream>>>(eqs, eks, values, w2, out);
}

// Round 3
// 70.401 us; speedup vs baseline: 1.4468x; 1.4468x over previous
//
#include <hip/hip_runtime.h>
#include <hip/hip_bf16.h>

#ifndef __has_builtin
#define __has_builtin(x) 0
#endif

__device__ __forceinline__ float fast_exp2(float x) {
#if __has_builtin(__builtin_amdgcn_exp2f)
  return __builtin_amdgcn_exp2f(x);
#else
  return __exp2f(x);
#endif
}
__device__ __forceinline__ float fast_rcp(float x) {
#if __has_builtin(__builtin_amdgcn_rcpf)
  return __builtin_amdgcn_rcpf(x);
#else
  return 1.0f / x;
#endif
}

#define B_   16
#define NQ_  256
#define NK_  256
#define D_   256
#define QT   4
// tanh(x) = 1 - 2/(1 + exp2(x * 2*log2(e)))
// Split-exp: exp2(s*(hq+hk)) = Eq * Ek with Eq=exp2(s*hq), Ek=exp2(s*hk).
#define TANH_SCALE 2.8853900817779268f
#define LOG2E      1.4426950408889634f

// ---------------- projection GEMM (f32 vector ALU; no f32 MFMA on CDNA4) ----
// z=0: Eq = exp2(TANH_SCALE*(queries@Wq + b1))   [4096,256]
// z=1: Ek = exp2(TANH_SCALE*(keys@Wk))           [4096,256]
__global__ __launch_bounds__(256) void proj_kernel(
    const float* __restrict__ queries, const float* __restrict__ keys,
    const float* __restrict__ Wq, const float* __restrict__ Wk,
    const float* __restrict__ b1,
    float* __restrict__ eqs, float* __restrict__ eks)
{
  const int z = blockIdx.z;
  const float* __restrict__ X = z ? keys : queries;
  const float* __restrict__ W = z ? Wk : Wq;
  float* __restrict__ O = z ? eks : eqs;

  const int m0 = blockIdx.x * 64;
  const int n0 = blockIdx.y * 64;
  const int t  = threadIdx.x;
  const int tx = t & 15, ty = t >> 4;

  __shared__ float As_t[64][68];  // [k][m], padded
  __shared__ float Bs[64][68];    // [k][n]

  float acc[4][4] = {};

  for (int kt = 0; kt < 4; ++kt) {
    const int k0 = kt * 64;
    #pragma unroll
    for (int i = 0; i < 4; ++i) {          // A tile, stored transposed
      int f = t + 256 * i;
      int row = f >> 4;
      int kc  = (f & 15) << 2;
      float4 v = *(const float4*)&X[(size_t)(m0 + row) * D_ + (k0 + kc)];
      As_t[kc + 0][row] = v.x; As_t[kc + 1][row] = v.y;
      As_t[kc + 2][row] = v.z; As_t[kc + 3][row] = v.w;
    }
    #pragma unroll
    for (int i = 0; i < 4; ++i) {          // B tile
      int f = t + 256 * i;
      int kr = f >> 4;
      int nc = (f & 15) << 2;
      *(float4*)&Bs[kr][nc] = *(const float4*)&W[(size_t)(k0 + kr) * D_ + (n0 + nc)];
    }
    __syncthreads();
    #pragma unroll 8
    for (int k = 0; k < 64; ++k) {
      float4 a = *(const float4*)&As_t[k][ty << 2];
      float4 b = *(const float4*)&Bs[k][tx << 2];
      float aa[4] = {a.x, a.y, a.z, a.w};
      float bb[4] = {b.x, b.y, b.z, b.w};
      #pragma unroll
      for (int i = 0; i < 4; ++i)
        #pragma unroll
        for (int j = 0; j < 4; ++j)
          acc[i][j] = fmaf(aa[i], bb[j], acc[i][j]);
    }
    __syncthreads();
  }

  float bias[4] = {0.f, 0.f, 0.f, 0.f};
  if (z == 0) {
    #pragma unroll
    for (int j = 0; j < 4; ++j) bias[j] = b1[n0 + (tx << 2) + j];
  }
  #pragma unroll
  for (int i = 0; i < 4; ++i)
    #pragma unroll
    for (int j = 0; j < 4; ++j)
      O[(size_t)(m0 + (ty << 2) + i) * D_ + n0 + (tx << 2) + j] =
          fast_exp2(TANH_SCALE * (acc[i][j] + bias[j]));
}

// ---------------- fused logits + softmax + PV (LDS-free hot loops) ---------
// Block = (b, 4 queries), 256 threads. Thread t = key t in logits.
// logit_eff = -2 * sum_d w2[d] * rcp(1 + Eq[d]*Ek[d])   (consts dropped)
// Eq/w2 have block-uniform addresses -> scalar (SMEM) loads, SGPR operands.
// PV: wave w owns keys 64w..64w+63 (p in its lanes' registers, broadcast via
// v_readlane), lane l owns d=4l..4l+3; 16 KB LDS pass combines the 4 waves.
// b = wgid&15 pins 2 batches per XCD (round-robin dispatch) -> L2-resident.
__global__ __launch_bounds__(256, 4) void attn_kernel(
    const float* __restrict__ eqs, const float* __restrict__ eks,
    const float* __restrict__ values, const float* __restrict__ w2,
    float* __restrict__ out)
{
  const int wgid = blockIdx.x;
  const int b  = wgid & 15;
  const int q0 = (wgid >> 4) * QT;
  const int t  = threadIdx.x;
  const int lane = t & 63, wave = t >> 6;

  __shared__ float pvred[4][QT][D_];          // 16 KB
  __shared__ float redA[4][QT], redB[4][QT];

  // ---- logits ----
  const float* __restrict__ ekrow = eks + ((size_t)(b * NK_) + t) * D_;
  const float* __restrict__ equni = eqs + ((size_t)(b * NQ_) + q0) * D_;
  float acc[QT] = {};
  #pragma unroll 4
  for (int d4 = 0; d4 < D_ / 4; ++d4) {
    float4 ekv = *(const float4*)&ekrow[d4 << 2];
    float4 wv  = *(const float4*)&w2[d4 << 2];           // uniform -> s_load
    float e[4] = {ekv.x, ekv.y, ekv.z, ekv.w};
    float w[4] = {wv.x, wv.y, wv.z, wv.w};
    #pragma unroll
    for (int qi = 0; qi < QT; ++qi) {
      float4 eqv = *(const float4*)&equni[(size_t)qi * D_ + (d4 << 2)];  // uniform
      float a[4] = {eqv.x, eqv.y, eqv.z, eqv.w};
      #pragma unroll
      for (int j = 0; j < 4; ++j) {
        float t0 = fmaf(a[j], e[j], 1.0f);
        acc[qi] = fmaf(w[j], fast_rcp(t0), acc[qi]);
      }
    }
  }

  float logit[QT];
  #pragma unroll
  for (int qi = 0; qi < QT; ++qi) logit[qi] = -2.0f * acc[qi];

  // ---- softmax over keys (block-wide) ----
  #pragma unroll
  for (int qi = 0; qi < QT; ++qi) {
    float v = logit[qi];
    #pragma unroll
    for (int off = 32; off; off >>= 1) v = fmaxf(v, __shfl_xor(v, off, 64));
    if (lane == 0) redA[wave][qi] = v;
  }
  __syncthreads();
  float mx[QT];
  #pragma unroll
  for (int qi = 0; qi < QT; ++qi)
    mx[qi] = fmaxf(fmaxf(redA[0][qi], redA[1][qi]),
                   fmaxf(redA[2][qi], redA[3][qi]));

  float p[QT];
  #pragma unroll
  for (int qi = 0; qi < QT; ++qi)
    p[qi] = fast_exp2((logit[qi] - mx[qi]) * LOG2E);
  #pragma unroll
  for (int qi = 0; qi < QT; ++qi) {
    float v = p[qi];
    #pragma unroll
    for (int off = 32; off; off >>= 1) v += __shfl_xor(v, off, 64);
    if (lane == 0) redB[wave][qi] = v;
  }
  __syncthreads();
  float pl[QT];
  #pragma unroll
  for (int qi = 0; qi < QT; ++qi) {
    float inv = fast_rcp(redB[0][qi] + redB[1][qi] + redB[2][qi] + redB[3][qi]);
    pl[qi] = p[qi] * inv;   // normalized weight for this thread's key
  }

  // ---- PV: wave-local over its 64 keys, p broadcast via readlane ----
  float ctx[QT][4] = {};
  const float* __restrict__ vbase =
      values + ((size_t)(b * NK_) + (wave << 6)) * D_ + (lane << 2);
  #pragma unroll 4
  for (int kl = 0; kl < 64; ++kl) {
    float4 vv = *(const float4*)&vbase[(size_t)kl * D_];
    float vz[4] = {vv.x, vv.y, vv.z, vv.w};
    #pragma unroll
    for (int qi = 0; qi < QT; ++qi) {
      float pk = __int_as_float(
          __builtin_amdgcn_readlane(__float_as_int(pl[qi]), kl));
      #pragma unroll
      for (int j = 0; j < 4; ++j)
        ctx[qi][j] = fmaf(pk, vz[j], ctx[qi][j]);
    }
  }

  // ---- combine 4 waves' partials via LDS (small) ----
  #pragma unroll
  for (int qi = 0; qi < QT; ++qi) {
    float4 v4; v4.x = ctx[qi][0]; v4.y = ctx[qi][1];
    v4.z = ctx[qi][2]; v4.w = ctx[qi][3];
    *(float4*)&pvred[wave][qi][lane << 2] = v4;
  }
  __syncthreads();
  #pragma unroll
  for (int qi = 0; qi < QT; ++qi) {
    float o = pvred[0][qi][t] + pvred[1][qi][t] +
              pvred[2][qi][t] + pvred[3][qi][t];
    out[((size_t)(b * NQ_) + q0 + qi) * D_ + t] = o;
  }
}

extern "C" void kernel_launch(void* const* d_in, const int* in_sizes, int n_in,
                              void* d_out, int out_size, void* d_ws, size_t ws_size,
                              hipStream_t stream)
{
  const float* keys    = (const float*)d_in[0];
  const float* queries = (const float*)d_in[1];
  const float* values  = (const float*)d_in[2];
  const float* Wk      = (const float*)d_in[3];
  const float* Wq      = (const float*)d_in[4];
  const float* b1      = (const float*)d_in[5];
  const float* w2      = (const float*)d_in[6];
  // d_in[7] = b2: dropped (softmax shift-invariance)

  float* eqs = (float*)d_ws;                       // [4096,256] f32, 4 MB
  float* eks = eqs + (size_t)B_ * NQ_ * D_;        // [4096,256] f32, 4 MB
  float* out = (float*)d_out;

  dim3 pgrid(B_ * NQ_ / 64, D_ / 64, 2);           // 64 x 4 x 2 = 512 blocks
  proj_kernel<<<pgrid, 256, 0, stream>>>(queries, keys, Wq, Wk, b1, eqs, eks);

  attn_kernel<<<dim3(B_ * NQ_ / QT), 256, 0, stream>>>(eqs, eks, values, w2, out);
}